// Round 2
// baseline (600.198 us; speedup 1.0000x reference)
//
#include <hip/hip_runtime.h>
#include <hip/hip_bf16.h>

typedef unsigned short u16;
using short8  = __attribute__((ext_vector_type(8))) short;
using float4v = __attribute__((ext_vector_type(4))) float;

#define N_POL  100000
#define N_TICK 20000
#define NNODE  120000
#define NEDGE  1000000
// EMB=128, HID=256, OUT=128

static __device__ __forceinline__ float b2f(u16 u) {
    return __uint_as_float(((unsigned)u) << 16);
}
static __device__ __forceinline__ u16 f2b(float f) {
    unsigned u = __float_as_uint(f);
    unsigned r = (u + 0x7FFFu + ((u >> 16) & 1u)) >> 16;
    return (u16)r;
}
static __device__ __forceinline__ float lde(const void* p, size_t i, int f32) {
    return f32 ? ((const float*)p)[i] : b2f(((const u16*)p)[i]);
}
// Runtime input-dtype detection on edge_weight (uniform [0,1)). See R4/R5 notes.
static __device__ __forceinline__ int detect_f32(const void* ew) {
    __shared__ int s_f32;
    if (threadIdx.x == 0) {
        const u16* p = (const u16*)ew;
        int huge = 0, allz = 1;
        for (int i = 0; i < 128; i += 2) {
            u16 b = p[i];
            if (b != 0) allz = 0;
            float v = b2f(b);
            if (!(fabsf(v) <= 4.0f)) huge = 1;
        }
        s_f32 = huge | allz;
    }
    __syncthreads();
    return s_f32;
}

// MFMA B-fragment address for K=256, N=256 packed weights (verified R7):
// element (k,n) -> ((n/16)*8 + k/32)*512 + (((k>>3)&3)*16 + (n&15))*8 + (k&7)
static __device__ __forceinline__ size_t frag_addr(int k, int n) {
    return ((size_t)((n >> 4) * 8 + (k >> 5)) * 64 + (((k >> 3) & 3) * 16 + (n & 15))) * 8
           + (k & 7);
}

// 16B global->LDS DMA (wave-uniform LDS base; HW adds lane*16)
static __device__ __forceinline__ void gload_lds16(const u16* g, u16* l) {
    __builtin_amdgcn_global_load_lds(
        (const __attribute__((address_space(1))) void*)g,
        (__attribute__((address_space(3))) void*)l, 16, 0, 0);
}

// ---------------- node feature build ----------------
__global__ __launch_bounds__(256) void build_pol(const void* __restrict__ pf,
                                                 const int* __restrict__ sid,
                                                 const void* __restrict__ Wp,
                                                 const void* __restrict__ bp,
                                                 const void* __restrict__ semb,
                                                 const void* __restrict__ ew,
                                                 u16* __restrict__ Xb) {
    int f32 = detect_f32(ew);
    int row = blockIdx.x * 2 + (threadIdx.x >> 7);
    int j = threadIdx.x & 127;
    float s = lde(bp, j, f32);
#pragma unroll
    for (int k = 0; k < 7; k++)
        s = fmaf(lde(pf, (size_t)row * 7 + k, f32), lde(Wp, k * 128 + j, f32), s);
    s = fmaxf(s, 0.f);
    s += lde(semb, (size_t)sid[row] * 128 + j, f32);
    Xb[(size_t)row * 128 + j] = f2b(s);
}

__global__ __launch_bounds__(256) void build_tick(const void* __restrict__ et,
                                                  const void* __restrict__ ew,
                                                  u16* __restrict__ Xb) {
    int f32 = detect_f32(ew);
    int idx = blockIdx.x * 256 + threadIdx.x;
    Xb[(size_t)N_POL * 128 + idx] = f2b(lde(et, idx, f32));
}

// ---------------- weight fragment prep ----------------
// GEMM1 B[k][n]: k<128 -> W1rel[k][n], else W1root[k-128][n]; N=256.
__global__ __launch_bounds__(256) void prep_wf1(const void* __restrict__ W1rel,
                                                const void* __restrict__ W1root,
                                                const void* __restrict__ ew,
                                                u16* __restrict__ Wf) {
    int f32 = detect_f32(ew);
    int idx = blockIdx.x * 256 + threadIdx.x;   // 65536
    int k = idx >> 8, n = idx & 255;
    float v = (k < 128) ? lde(W1rel, (size_t)k * 256 + n, f32)
                        : lde(W1root, (size_t)(k - 128) * 256 + n, f32);
    Wf[frag_addr(k, n)] = f2b(v);
}

// GEMM2 B[k][n]: n<128 -> W2rel[k][n], else W2root[k][n-128]; N=256.
__global__ __launch_bounds__(256) void prep_wf2(const void* __restrict__ W2rel,
                                                const void* __restrict__ W2root,
                                                const void* __restrict__ ew,
                                                u16* __restrict__ Wf) {
    int f32 = detect_f32(ew);
    int idx = blockIdx.x * 256 + threadIdx.x;   // 65536
    int k = idx >> 8, n = idx & 255;
    float v = (n < 128) ? lde(W2rel, (size_t)k * 128 + n, f32)
                        : lde(W2root, (size_t)k * 128 + (n - 128), f32);
    Wf[frag_addr(k, n)] = f2b(v);
}

// ---------------- CSR build ----------------
__global__ __launch_bounds__(256) void hist_dst(const int* __restrict__ ei,
                                                int* __restrict__ count) {
    int e = blockIdx.x * 256 + threadIdx.x;
    if (e < NEDGE) atomicAdd(&count[ei[NEDGE + e]], 1);
}

__global__ __launch_bounds__(256) void scan1(const int* __restrict__ count,
                                             int* __restrict__ row_tmp,
                                             int* __restrict__ bsum) {
    __shared__ int sd[256];
    int t = threadIdx.x;
    int i = blockIdx.x * 256 + t;
    int c = (i < NNODE) ? count[i] : 0;
    sd[t] = c;
    __syncthreads();
#pragma unroll
    for (int off = 1; off < 256; off <<= 1) {
        int v = (t >= off) ? sd[t - off] : 0;
        __syncthreads();
        sd[t] += v;
        __syncthreads();
    }
    if (i < NNODE) row_tmp[i] = sd[t] - c;
    if (t == 255) bsum[blockIdx.x] = sd[t];
}

__global__ __launch_bounds__(512) void scan2(int* __restrict__ bsum, int nb) {
    __shared__ int sd[512];
    int t = threadIdx.x;
    int v = (t < nb) ? bsum[t] : 0;
    sd[t] = v;
    __syncthreads();
#pragma unroll
    for (int off = 1; off < 512; off <<= 1) {
        int u = (t >= off) ? sd[t - off] : 0;
        __syncthreads();
        sd[t] += u;
        __syncthreads();
    }
    if (t < nb) bsum[t] = sd[t] - v;
}

__global__ __launch_bounds__(256) void scan3(const int* __restrict__ row_tmp,
                                             const int* __restrict__ bsum,
                                             int* __restrict__ row_start,
                                             int* __restrict__ cursor) {
    int i = blockIdx.x * 256 + threadIdx.x;
    if (i < NNODE) {
        int v = row_tmp[i] + bsum[blockIdx.x];
        row_start[i] = v;
        cursor[i] = v;
    }
    if (i == 0) row_start[NNODE] = NEDGE;
}

__global__ __launch_bounds__(256) void fill_csr(const int* __restrict__ ei,
                                                const void* __restrict__ ew,
                                                int* __restrict__ cursor,
                                                int* __restrict__ ssrc,
                                                u16* __restrict__ sw) {
    int f32 = detect_f32(ew);
    int e = blockIdx.x * 256 + threadIdx.x;
    if (e >= NEDGE) return;
    int src = ei[e];
    int dst = ei[NEDGE + e];
    int pos = atomicAdd(&cursor[dst], 1);
    ssrc[pos] = src;
    sw[pos] = f2b(lde(ew, e, f32));
}

// ---------------- gather1: agg[n] = sum_e w_e * S[src_e]  (bf16 out, pitch 128) ----
__global__ __launch_bounds__(256) void gather128(const int* __restrict__ row_start,
                                                 const int* __restrict__ ssrc,
                                                 const u16* __restrict__ sw,
                                                 const u16* __restrict__ S,
                                                 u16* __restrict__ agg) {
    int n = blockIdx.x * 4 + (threadIdx.x >> 6);
    int lane = threadIdx.x & 63;
    int s0 = row_start[n], s1 = row_start[n + 1];
    float a0 = 0.f, a1 = 0.f;
    int e = s0;
    for (; e + 8 <= s1; e += 8) {
        float w[8]; ushort2 xv[8];
#pragma unroll
        for (int u = 0; u < 8; u++) {
            int sr = ssrc[e + u];
            w[u] = b2f(sw[e + u]);
            xv[u] = *(const ushort2*)(S + (size_t)sr * 128 + lane * 2);
        }
#pragma unroll
        for (int u = 0; u < 8; u++) {
            a0 = fmaf(b2f(xv[u].x), w[u], a0);
            a1 = fmaf(b2f(xv[u].y), w[u], a1);
        }
    }
    for (; e < s1; e++) {
        int sr = ssrc[e];
        float w = b2f(sw[e]);
        ushort2 xv = *(const ushort2*)(S + (size_t)sr * 128 + lane * 2);
        a0 = fmaf(b2f(xv.x), w, a0);
        a1 = fmaf(b2f(xv.y), w, a1);
    }
    ushort2 o;
    o.x = f2b(a0);
    o.y = f2b(a1);
    *(ushort2*)(agg + (size_t)n * 128 + lane * 2) = o;
}

// ---------------- gather2 + add P: out[n] = P[n] + sum_e w_e * T2[src_e] ----------
__global__ __launch_bounds__(256) void gather_add(const int* __restrict__ row_start,
                                                  const int* __restrict__ ssrc,
                                                  const u16* __restrict__ sw,
                                                  const u16* __restrict__ T2,
                                                  const u16* __restrict__ P,
                                                  const void* __restrict__ ew,
                                                  void* __restrict__ out) {
    int f32 = detect_f32(ew);
    int n = blockIdx.x * 4 + (threadIdx.x >> 6);
    int lane = threadIdx.x & 63;
    int s0 = row_start[n], s1 = row_start[n + 1];
    float a0 = 0.f, a1 = 0.f;
    int e = s0;
    for (; e + 8 <= s1; e += 8) {
        float w[8]; ushort2 xv[8];
#pragma unroll
        for (int u = 0; u < 8; u++) {
            int sr = ssrc[e + u];
            w[u] = b2f(sw[e + u]);
            xv[u] = *(const ushort2*)(T2 + (size_t)sr * 128 + lane * 2);
        }
#pragma unroll
        for (int u = 0; u < 8; u++) {
            a0 = fmaf(b2f(xv[u].x), w[u], a0);
            a1 = fmaf(b2f(xv[u].y), w[u], a1);
        }
    }
    for (; e < s1; e++) {
        int sr = ssrc[e];
        float w = b2f(sw[e]);
        ushort2 xv = *(const ushort2*)(T2 + (size_t)sr * 128 + lane * 2);
        a0 = fmaf(b2f(xv.x), w, a0);
        a1 = fmaf(b2f(xv.y), w, a1);
    }
    ushort2 pv = *(const ushort2*)(P + (size_t)n * 128 + lane * 2);
    float v0 = a0 + b2f(pv.x);
    float v1 = a1 + b2f(pv.y);
    if (f32) {
        float2 s; s.x = v0; s.y = v1;
        *(float2*)((float*)out + (size_t)n * 128 + lane * 2) = s;
    } else {
        ushort2 s; s.x = f2b(v0); s.y = f2b(v1);
        *(ushort2*)((u16*)out + (size_t)n * 128 + lane * 2) = s;
    }
}

// ---------------- fused dual MFMA GEMM (v2: DMA-staged A) ----------------
// Phase 1: H = relu([agg|Xb] @ Wf1 + b1)   (64 rows x 256 cols)
// Phase 2: [T2 | P] = H @ Wf2 (+b2 on P half)  -> global
// Block 256 thr (4 waves 2x2: wy=row-half, wx=col-half). Wave tile 32r x 128c.
// LDSU (32 KB) holds A-frags during phase 1, then H-frags for phase 2 (A dead first).
// Frag order: element (row,k) at u16 index ((k>>3)*64 + row)*8 + (k&7).
// A staged via global_load_lds: chunk C=kq*64+row, dest byte C*16 (wave-uniform base
// kq*1024 + lane*16, row=lane, kq=i*4+wid uniform per wave per round).
__global__ __launch_bounds__(256) void fused_gemm(const u16* __restrict__ agg,
                                                  const u16* __restrict__ Xb,
                                                  const u16* __restrict__ Wf1,
                                                  const u16* __restrict__ Wf2,
                                                  const void* __restrict__ b1,
                                                  const void* __restrict__ b2,
                                                  u16* __restrict__ T2,
                                                  u16* __restrict__ P,
                                                  const void* __restrict__ ew, int M) {
    int f32 = detect_f32(ew);
    __shared__ u16 LDSU[32 * 64 * 8];   // 32 KB, A-frags then H-frags
    const int row0 = blockIdx.x * 64;
    const int wid = threadIdx.x >> 6;
    const int lane = threadIdx.x & 63;
    const int wy = wid >> 1, wx = wid & 1;
    const int q = lane >> 4, lm = lane & 15;
    const int rw = wy * 32;             // wave row base (block-local)

    // ---- stage A tile (64 rows x K=256: cols 0-127 agg, 128-255 Xb) ----
    {
        const u16* aBase = agg + ((size_t)row0 + lane) * 128;
        const u16* xBase = Xb + ((size_t)row0 + lane) * 128;
#pragma unroll
        for (int i = 0; i < 8; i++) {
            int kq = i * 4 + wid;       // wave-uniform, covers 0..31 across waves/rounds
            const u16* src = (kq < 16) ? (aBase + kq * 8) : (xBase + (kq - 16) * 8);
            gload_lds16(src, LDSU + (size_t)kq * 512);
        }
    }
    __syncthreads();   // drains vmcnt (global_load_lds) before any ds_read

    // ---- phase 1: MFMAs only (epilogue deferred so LDSU can be reused) ----
    float4v acc[2][2][4];   // [h][ti][tj]
#pragma unroll
    for (int h = 0; h < 2; h++)
#pragma unroll
        for (int i = 0; i < 2; i++)
#pragma unroll
            for (int j = 0; j < 4; j++) acc[h][i][j] = (float4v){0.f, 0.f, 0.f, 0.f};
#pragma unroll
    for (int kb = 0; kb < 8; kb++) {
        short8 a[2];
#pragma unroll
        for (int ti = 0; ti < 2; ti++) {
            int rl = rw + ti * 16 + lm;
            a[ti] = *(const short8*)(LDSU + ((size_t)(kb * 4 + q) * 64 + rl) * 8);
        }
#pragma unroll
        for (int h = 0; h < 2; h++) {
            short8 b[4];
#pragma unroll
            for (int tj = 0; tj < 4; tj++) {
                int nt = wx * 8 + h * 4 + tj;
                b[tj] = *(const short8*)(Wf1 + ((size_t)(nt * 8 + kb) * 64 + lane) * 8);
            }
#pragma unroll
            for (int ti = 0; ti < 2; ti++)
#pragma unroll
                for (int tj = 0; tj < 4; tj++)
                    acc[h][ti][tj] = __builtin_amdgcn_mfma_f32_16x16x32_bf16(
                        a[ti], b[tj], acc[h][ti][tj], 0, 0, 0);
        }
    }
    __syncthreads();   // all A reads done; LDSU now reusable for H

    // ---- phase-1 epilogue: bias + relu -> LDSU (phase-2 A-frag order) ----
#pragma unroll
    for (int h = 0; h < 2; h++) {
#pragma unroll
        for (int tj = 0; tj < 4; tj++) {
            int col = wx * 128 + (h * 4 + tj) * 16 + lm;
            float bv = lde(b1, col, f32);
            int kq2 = col >> 3, jj = col & 7;
#pragma unroll
            for (int ti = 0; ti < 2; ti++) {
                int rl = rw + ti * 16 + q * 4;
#pragma unroll
                for (int r = 0; r < 4; r++) {
                    float v = fmaxf(acc[h][ti][tj][r] + bv, 0.f);
                    LDSU[((size_t)kq2 * 64 + rl + r) * 8 + jj] = f2b(v);
                }
            }
        }
    }
    __syncthreads();

    // ---- phase 2 ----
    float4v acc2[2][2][4];
#pragma unroll
    for (int h = 0; h < 2; h++)
#pragma unroll
        for (int i = 0; i < 2; i++)
#pragma unroll
            for (int j = 0; j < 4; j++) acc2[h][i][j] = (float4v){0.f, 0.f, 0.f, 0.f};
#pragma unroll
    for (int kb = 0; kb < 8; kb++) {
        short8 a[2];
#pragma unroll
        for (int ti = 0; ti < 2; ti++) {
            int rl = rw + ti * 16 + lm;
            a[ti] = *(const short8*)(LDSU + ((size_t)(kb * 4 + q) * 64 + rl) * 8);
        }
#pragma unroll
        for (int h = 0; h < 2; h++) {
            short8 b[4];
#pragma unroll
            for (int tj = 0; tj < 4; tj++) {
                int nt = wx * 8 + h * 4 + tj;
                b[tj] = *(const short8*)(Wf2 + ((size_t)(nt * 8 + kb) * 64 + lane) * 8);
            }
#pragma unroll
            for (int ti = 0; ti < 2; ti++)
#pragma unroll
                for (int tj = 0; tj < 4; tj++)
                    acc2[h][ti][tj] = __builtin_amdgcn_mfma_f32_16x16x32_bf16(
                        a[ti], b[tj], acc2[h][ti][tj], 0, 0, 0);
        }
    }

    // ---- phase-2 epilogue: cols <128 -> T2 (no bias), >=128 -> P (+b2) ----
#pragma unroll
    for (int h = 0; h < 2; h++) {
#pragma unroll
        for (int tj = 0; tj < 4; tj++) {
            int n_g = wx * 128 + (h * 4 + tj) * 16 + lm;
            float bv;
            u16* dst;
            if (n_g < 128) {
                bv = 0.f;
                dst = T2 + n_g;
            } else {
                bv = lde(b2, n_g - 128, f32);
                dst = P + (n_g - 128);
            }
#pragma unroll
            for (int ti = 0; ti < 2; ti++) {
                int rbase = row0 + rw + ti * 16 + q * 4;
#pragma unroll
                for (int r = 0; r < 4; r++) {
                    int row = rbase + r;
                    if (row < M)
                        dst[(size_t)row * 128] = f2b(acc2[h][ti][tj][r] + bv);
                }
            }
        }
    }
}

extern "C" void kernel_launch(void* const* d_in, const int* in_sizes, int n_in,
                              void* d_out, int out_size, void* d_ws, size_t ws_size,
                              hipStream_t stream) {
    const void* pf     = d_in[0];
    const int*  sid    = (const int*)d_in[1];
    const int*  ei     = (const int*)d_in[2];
    const void* ew     = d_in[3];
    const void* Wp     = d_in[4];
    const void* bp     = d_in[5];
    const void* semb   = d_in[6];
    const void* et     = d_in[7];
    const void* W1rel  = d_in[8];
    const void* b1     = d_in[9];
    const void* W1root = d_in[10];
    const void* W2rel  = d_in[11];
    const void* b2     = d_in[12];
    const void* W2root = d_in[13];

    // Workspace (~100.3 MB < proven 122.88 MB budget):
    char* w = (char*)d_ws;
    u16* agg       = (u16*)w;                    // bf16 [N,128]
    u16* T2        = (u16*)(w + 30720000);       // bf16 [N,128]
    u16* P         = (u16*)(w + 61440000);       // bf16 [N,128]
    u16* Wf1       = (u16*)(w + 92160000);       // 131072 B
    u16* Wf2       = (u16*)(w + 92291072);       // 131072 B
    int* ssrc      = (int*)(w + 92422144);       // int [E]
    u16* sw        = (u16*)(w + 96422144);       // bf16 [E]
    int* row_start = (int*)(w + 98422144);       // int [N+1]
    int* row_tmp   = (int*)(w + 98902148);
    int* cursor    = (int*)(w + 99382148);
    int* count     = (int*)(w + 99862148);
    int* bsum      = (int*)(w + 100342148);
    u16* Xb        = (u16*)d_out;                // bf16 [N,128] scratch until fused_gemm done

    const int EB = (NEDGE + 255) / 256;   // 3907
    const int NB = (NNODE + 255) / 256;   // 469
    const int GB = (NNODE + 63) / 64;     // 1875

    // CSR build (reused by both gathers)
    hipMemsetAsync(count, 0, NNODE * sizeof(int), stream);
    hist_dst<<<EB, 256, 0, stream>>>(ei, count);
    scan1<<<NB, 256, 0, stream>>>(count, row_tmp, bsum);
    scan2<<<1, 512, 0, stream>>>(bsum, NB);
    scan3<<<NB, 256, 0, stream>>>(row_tmp, bsum, row_start, cursor);
    fill_csr<<<EB, 256, 0, stream>>>(ei, ew, cursor, ssrc, sw);

    // weight fragments
    prep_wf1<<<256, 256, 0, stream>>>(W1rel, W1root, ew, Wf1);
    prep_wf2<<<256, 256, 0, stream>>>(W2rel, W2root, ew, Wf2);

    // node features -> Xb (d_out)
    build_pol<<<N_POL / 2, 256, 0, stream>>>(pf, sid, Wp, bp, semb, ew, Xb);
    build_tick<<<(N_TICK * 128) / 256, 256, 0, stream>>>(et, ew, Xb);

    // layer-1 aggregation
    gather128<<<NNODE / 4, 256, 0, stream>>>(row_start, ssrc, sw, Xb, agg);

    // fused: H = relu([agg|Xb]@Wf1+b1) in LDS; [T2|P] = H@Wf2 (+b2 on P)
    fused_gemm<<<GB, 256, 0, stream>>>(agg, Xb, Wf1, Wf2, b1, b2, T2, P, ew, NNODE);

    // out = P + segment_sum(w * T2)   (d_out scratch Xb is dead now)
    gather_add<<<NNODE / 4, 256, 0, stream>>>(row_start, ssrc, sw, T2, P, ew, d_out);
}

// Round 3
// 577.388 us; speedup vs baseline: 1.0395x; 1.0395x over previous
//
#include <hip/hip_runtime.h>
#include <hip/hip_bf16.h>

typedef unsigned short u16;
using short8  = __attribute__((ext_vector_type(8))) short;
using float4v = __attribute__((ext_vector_type(4))) float;

#define N_POL  100000
#define N_TICK 20000
#define NNODE  120000
#define NEDGE  1000000
// EMB=128, HID=256, OUT=128

static __device__ __forceinline__ float b2f(u16 u) {
    return __uint_as_float(((unsigned)u) << 16);
}
static __device__ __forceinline__ u16 f2b(float f) {
    unsigned u = __float_as_uint(f);
    unsigned r = (u + 0x7FFFu + ((u >> 16) & 1u)) >> 16;
    return (u16)r;
}
static __device__ __forceinline__ float lde(const void* p, size_t i, int f32) {
    return f32 ? ((const float*)p)[i] : b2f(((const u16*)p)[i]);
}

// MFMA B-fragment address for K=256, N=256 packed weights (verified R7):
// element (k,n) -> ((n/16)*8 + k/32)*512 + (((k>>3)&3)*16 + (n&15))*8 + (k&7)
static __device__ __forceinline__ size_t frag_addr(int k, int n) {
    return ((size_t)((n >> 4) * 8 + (k >> 5)) * 64 + (((k >> 3) & 3) * 16 + (n & 15))) * 8
           + (k & 7);
}

// 16B global->LDS DMA (wave-uniform LDS base; HW adds lane*16)
static __device__ __forceinline__ void gload_lds16(const u16* g, u16* l) {
    __builtin_amdgcn_global_load_lds(
        (const __attribute__((address_space(1))) void*)g,
        (__attribute__((address_space(3))) void*)l, 16, 0, 0);
}

// ---------------- one-shot input-dtype detection ----------------
// Runtime input-dtype detection on edge_weight (uniform [0,1)). See R4/R5 notes.
// Hoisted to a single tiny kernel: consumers do one uniform load instead of a
// 64-deep serial load chain + barrier per block.
__global__ void detect_k(const void* __restrict__ ew, int* __restrict__ flag) {
    if (threadIdx.x == 0) {
        const u16* p = (const u16*)ew;
        int huge = 0, allz = 1;
        for (int i = 0; i < 128; i += 2) {
            u16 b = p[i];
            if (b != 0) allz = 0;
            float v = b2f(b);
            if (!(fabsf(v) <= 4.0f)) huge = 1;
        }
        *flag = huge | allz;
    }
}

// ---------------- node feature build ----------------
__global__ __launch_bounds__(256) void build_pol(const void* __restrict__ pf,
                                                 const int* __restrict__ sid,
                                                 const void* __restrict__ Wp,
                                                 const void* __restrict__ bp,
                                                 const void* __restrict__ semb,
                                                 const int* __restrict__ flag,
                                                 u16* __restrict__ Xb) {
    const int f32 = *flag;
    int row = blockIdx.x * 2 + (threadIdx.x >> 7);
    int j = threadIdx.x & 127;
    float s = lde(bp, j, f32);
#pragma unroll
    for (int k = 0; k < 7; k++)
        s = fmaf(lde(pf, (size_t)row * 7 + k, f32), lde(Wp, k * 128 + j, f32), s);
    s = fmaxf(s, 0.f);
    s += lde(semb, (size_t)sid[row] * 128 + j, f32);
    Xb[(size_t)row * 128 + j] = f2b(s);
}

__global__ __launch_bounds__(256) void build_tick(const void* __restrict__ et,
                                                  const int* __restrict__ flag,
                                                  u16* __restrict__ Xb) {
    const int f32 = *flag;
    int idx = blockIdx.x * 256 + threadIdx.x;
    Xb[(size_t)N_POL * 128 + idx] = f2b(lde(et, idx, f32));
}

// ---------------- weight fragment prep ----------------
// GEMM1 B[k][n]: k<128 -> W1rel[k][n], else W1root[k-128][n]; N=256.
__global__ __launch_bounds__(256) void prep_wf1(const void* __restrict__ W1rel,
                                                const void* __restrict__ W1root,
                                                const int* __restrict__ flag,
                                                u16* __restrict__ Wf) {
    const int f32 = *flag;
    int idx = blockIdx.x * 256 + threadIdx.x;   // 65536
    int k = idx >> 8, n = idx & 255;
    float v = (k < 128) ? lde(W1rel, (size_t)k * 256 + n, f32)
                        : lde(W1root, (size_t)(k - 128) * 256 + n, f32);
    Wf[frag_addr(k, n)] = f2b(v);
}

// GEMM2 B[k][n]: n<128 -> W2rel[k][n], else W2root[k][n-128]; N=256.
__global__ __launch_bounds__(256) void prep_wf2(const void* __restrict__ W2rel,
                                                const void* __restrict__ W2root,
                                                const int* __restrict__ flag,
                                                u16* __restrict__ Wf) {
    const int f32 = *flag;
    int idx = blockIdx.x * 256 + threadIdx.x;   // 65536
    int k = idx >> 8, n = idx & 255;
    float v = (n < 128) ? lde(W2rel, (size_t)k * 128 + n, f32)
                        : lde(W2root, (size_t)k * 128 + (n - 128), f32);
    Wf[frag_addr(k, n)] = f2b(v);
}

// ---------------- CSR build ----------------
__global__ __launch_bounds__(256) void hist_dst(const int* __restrict__ ei,
                                                int* __restrict__ count) {
    int e = blockIdx.x * 256 + threadIdx.x;
    if (e < NEDGE) atomicAdd(&count[ei[NEDGE + e]], 1);
}

__global__ __launch_bounds__(256) void scan1(const int* __restrict__ count,
                                             int* __restrict__ row_tmp,
                                             int* __restrict__ bsum) {
    __shared__ int sd[256];
    int t = threadIdx.x;
    int i = blockIdx.x * 256 + t;
    int c = (i < NNODE) ? count[i] : 0;
    sd[t] = c;
    __syncthreads();
#pragma unroll
    for (int off = 1; off < 256; off <<= 1) {
        int v = (t >= off) ? sd[t - off] : 0;
        __syncthreads();
        sd[t] += v;
        __syncthreads();
    }
    if (i < NNODE) row_tmp[i] = sd[t] - c;
    if (t == 255) bsum[blockIdx.x] = sd[t];
}

__global__ __launch_bounds__(512) void scan2(int* __restrict__ bsum, int nb) {
    __shared__ int sd[512];
    int t = threadIdx.x;
    int v = (t < nb) ? bsum[t] : 0;
    sd[t] = v;
    __syncthreads();
#pragma unroll
    for (int off = 1; off < 512; off <<= 1) {
        int u = (t >= off) ? sd[t - off] : 0;
        __syncthreads();
        sd[t] += u;
        __syncthreads();
    }
    if (t < nb) bsum[t] = sd[t] - v;
}

__global__ __launch_bounds__(256) void scan3(const int* __restrict__ row_tmp,
                                             const int* __restrict__ bsum,
                                             int* __restrict__ row_start,
                                             int* __restrict__ cursor) {
    int i = blockIdx.x * 256 + threadIdx.x;
    if (i < NNODE) {
        int v = row_tmp[i] + bsum[blockIdx.x];
        row_start[i] = v;
        cursor[i] = v;
    }
    if (i == 0) row_start[NNODE] = NEDGE;
}

__global__ __launch_bounds__(256) void fill_csr(const int* __restrict__ ei,
                                                const void* __restrict__ ew,
                                                const int* __restrict__ flag,
                                                int* __restrict__ cursor,
                                                int* __restrict__ ssrc,
                                                u16* __restrict__ sw) {
    const int f32 = *flag;
    int e = blockIdx.x * 256 + threadIdx.x;
    if (e >= NEDGE) return;
    int src = ei[e];
    int dst = ei[NEDGE + e];
    int pos = atomicAdd(&cursor[dst], 1);
    ssrc[pos] = src;
    sw[pos] = f2b(lde(ew, e, f32));
}

// ---------------- gather1: agg[n] = sum_e w_e * S[src_e]  (bf16 out, pitch 128) ----
__global__ __launch_bounds__(256) void gather128(const int* __restrict__ row_start,
                                                 const int* __restrict__ ssrc,
                                                 const u16* __restrict__ sw,
                                                 const u16* __restrict__ S,
                                                 u16* __restrict__ agg) {
    int n = blockIdx.x * 4 + (threadIdx.x >> 6);
    int lane = threadIdx.x & 63;
    int s0 = row_start[n], s1 = row_start[n + 1];
    float a0 = 0.f, a1 = 0.f;
    int e = s0;
    for (; e + 8 <= s1; e += 8) {
        float w[8]; ushort2 xv[8];
#pragma unroll
        for (int u = 0; u < 8; u++) {
            int sr = ssrc[e + u];
            w[u] = b2f(sw[e + u]);
            xv[u] = *(const ushort2*)(S + (size_t)sr * 128 + lane * 2);
        }
#pragma unroll
        for (int u = 0; u < 8; u++) {
            a0 = fmaf(b2f(xv[u].x), w[u], a0);
            a1 = fmaf(b2f(xv[u].y), w[u], a1);
        }
    }
    for (; e < s1; e++) {
        int sr = ssrc[e];
        float w = b2f(sw[e]);
        ushort2 xv = *(const ushort2*)(S + (size_t)sr * 128 + lane * 2);
        a0 = fmaf(b2f(xv.x), w, a0);
        a1 = fmaf(b2f(xv.y), w, a1);
    }
    ushort2 o;
    o.x = f2b(a0);
    o.y = f2b(a1);
    *(ushort2*)(agg + (size_t)n * 128 + lane * 2) = o;
}

// ---------------- gather2 + add P: out[n] = P[n] + sum_e w_e * T2[src_e] ----------
__global__ __launch_bounds__(256) void gather_add(const int* __restrict__ row_start,
                                                  const int* __restrict__ ssrc,
                                                  const u16* __restrict__ sw,
                                                  const u16* __restrict__ T2,
                                                  const u16* __restrict__ P,
                                                  const int* __restrict__ flag,
                                                  void* __restrict__ out) {
    const int f32 = *flag;
    int n = blockIdx.x * 4 + (threadIdx.x >> 6);
    int lane = threadIdx.x & 63;
    int s0 = row_start[n], s1 = row_start[n + 1];
    float a0 = 0.f, a1 = 0.f;
    int e = s0;
    for (; e + 8 <= s1; e += 8) {
        float w[8]; ushort2 xv[8];
#pragma unroll
        for (int u = 0; u < 8; u++) {
            int sr = ssrc[e + u];
            w[u] = b2f(sw[e + u]);
            xv[u] = *(const ushort2*)(T2 + (size_t)sr * 128 + lane * 2);
        }
#pragma unroll
        for (int u = 0; u < 8; u++) {
            a0 = fmaf(b2f(xv[u].x), w[u], a0);
            a1 = fmaf(b2f(xv[u].y), w[u], a1);
        }
    }
    for (; e < s1; e++) {
        int sr = ssrc[e];
        float w = b2f(sw[e]);
        ushort2 xv = *(const ushort2*)(T2 + (size_t)sr * 128 + lane * 2);
        a0 = fmaf(b2f(xv.x), w, a0);
        a1 = fmaf(b2f(xv.y), w, a1);
    }
    ushort2 pv = *(const ushort2*)(P + (size_t)n * 128 + lane * 2);
    float v0 = a0 + b2f(pv.x);
    float v1 = a1 + b2f(pv.y);
    if (f32) {
        float2 s; s.x = v0; s.y = v1;
        *(float2*)((float*)out + (size_t)n * 128 + lane * 2) = s;
    } else {
        ushort2 s; s.x = f2b(v0); s.y = f2b(v1);
        *(ushort2*)((u16*)out + (size_t)n * 128 + lane * 2) = s;
    }
}

// ---------------- fused dual MFMA GEMM (v3: coalesced DMA + XOR-swizzled A) -------
// Phase 1: H = relu([agg|Xb] @ Wf1 + b1)   (64 rows x 256 cols)
// Phase 2: [T2 | P] = H @ Wf2 (+b2 on P half)  -> global
// Block 256 thr (4 waves 2x2: wy=row-half, wx=col-half). Wave tile 32r x 128c.
// LDSU (32 KB): A tile row-major [64 rows][32 chunks of 16B], XOR-swizzled
// (chunk_in_lds = chunk_global ^ (row&7)); then reused for H frags (A dead first).
// DMA: instr t (wave-uniform) -> LDS bytes t*1024; lanes 0-31 = row 2t (512B
// contiguous per row), 32-63 = row 2t+1. Global src pre-swizzled so each DMA
// instr fetches 16 fully-used 64B lines (2 rows x [agg|Xb]), zero redundancy.
// H frag order (phase 2 A): element (row,k) at u16 index ((k>>3)*64 + row)*8 + (k&7).
__global__ __launch_bounds__(256, 4) void fused_gemm(const u16* __restrict__ agg,
                                                     const u16* __restrict__ Xb,
                                                     const u16* __restrict__ Wf1,
                                                     const u16* __restrict__ Wf2,
                                                     const void* __restrict__ b1,
                                                     const void* __restrict__ b2,
                                                     u16* __restrict__ T2,
                                                     u16* __restrict__ P,
                                                     const int* __restrict__ flag,
                                                     int M) {
    const int f32 = *flag;
    __shared__ u16 LDSU[32 * 64 * 8];   // 32 KB, A tile then H frags
    const int row0 = blockIdx.x * 64;
    const int wid = threadIdx.x >> 6;
    const int lane = threadIdx.x & 63;
    const int wy = wid >> 1, wx = wid & 1;
    const int q = lane >> 4, lm = lane & 15;
    const int rw = wy * 32;             // wave row base (block-local)

    // ---- stage A tile (64 rows x K=256: chunks 0-15 agg, 16-31 Xb) ----
    {
        int rrow = 2 * wid + (lane >> 5);          // row parity part for t=wid base
        int kqL = lane & 31;
#pragma unroll
        for (int i = 0; i < 8; i++) {
            int t = i * 4 + wid;                   // wave-uniform instr index 0..31
            int row = 2 * t + (lane >> 5);         // 0..63
            int kqG = kqL ^ (row & 7);             // pre-swizzled source chunk
            const u16* src = (kqG < 16)
                ? agg + ((size_t)(row0 + row)) * 128 + kqG * 8
                : Xb + ((size_t)(row0 + row)) * 128 + (kqG - 16) * 8;
            gload_lds16(src, LDSU + (size_t)t * 512);
        }
        (void)rrow;
    }
    __syncthreads();   // drains vmcnt (global_load_lds) before any ds_read

    // ---- phase 1: MFMAs only (epilogue deferred so LDSU can be reused) ----
    float4v acc[2][2][4];   // [h][ti][tj]
#pragma unroll
    for (int h = 0; h < 2; h++)
#pragma unroll
        for (int i = 0; i < 2; i++)
#pragma unroll
            for (int j = 0; j < 4; j++) acc[h][i][j] = (float4v){0.f, 0.f, 0.f, 0.f};
#pragma unroll
    for (int kb = 0; kb < 8; kb++) {
        short8 a[2];
#pragma unroll
        for (int ti = 0; ti < 2; ti++) {
            int rl = rw + ti * 16 + lm;
            int chunk = (kb * 4 + q) ^ (rl & 7);   // XOR-swizzle read side
            a[ti] = *(const short8*)(LDSU + (size_t)rl * 256 + chunk * 8);
        }
#pragma unroll
        for (int h = 0; h < 2; h++) {
            short8 b[4];
#pragma unroll
            for (int tj = 0; tj < 4; tj++) {
                int nt = wx * 8 + h * 4 + tj;
                b[tj] = *(const short8*)(Wf1 + ((size_t)(nt * 8 + kb) * 64 + lane) * 8);
            }
#pragma unroll
            for (int ti = 0; ti < 2; ti++)
#pragma unroll
                for (int tj = 0; tj < 4; tj++)
                    acc[h][ti][tj] = __builtin_amdgcn_mfma_f32_16x16x32_bf16(
                        a[ti], b[tj], acc[h][ti][tj], 0, 0, 0);
        }
    }
    __syncthreads();   // all A reads done; LDSU now reusable for H

    // ---- phase-1 epilogue: bias + relu -> LDSU (phase-2 A-frag order) ----
#pragma unroll
    for (int h = 0; h < 2; h++) {
#pragma unroll
        for (int tj = 0; tj < 4; tj++) {
            int col = wx * 128 + (h * 4 + tj) * 16 + lm;
            float bv = lde(b1, col, f32);
            int kq2 = col >> 3, jj = col & 7;
#pragma unroll
            for (int ti = 0; ti < 2; ti++) {
                int rl = rw + ti * 16 + q * 4;
#pragma unroll
                for (int r = 0; r < 4; r++) {
                    float v = fmaxf(acc[h][ti][tj][r] + bv, 0.f);
                    LDSU[((size_t)kq2 * 64 + rl + r) * 8 + jj] = f2b(v);
                }
            }
        }
    }
    __syncthreads();

    // ---- phase 2 ----
    float4v acc2[2][2][4];
#pragma unroll
    for (int h = 0; h < 2; h++)
#pragma unroll
        for (int i = 0; i < 2; i++)
#pragma unroll
            for (int j = 0; j < 4; j++) acc2[h][i][j] = (float4v){0.f, 0.f, 0.f, 0.f};
#pragma unroll
    for (int kb = 0; kb < 8; kb++) {
        short8 a[2];
#pragma unroll
        for (int ti = 0; ti < 2; ti++) {
            int rl = rw + ti * 16 + lm;
            a[ti] = *(const short8*)(LDSU + ((size_t)(kb * 4 + q) * 64 + rl) * 8);
        }
#pragma unroll
        for (int h = 0; h < 2; h++) {
            short8 b[4];
#pragma unroll
            for (int tj = 0; tj < 4; tj++) {
                int nt = wx * 8 + h * 4 + tj;
                b[tj] = *(const short8*)(Wf2 + ((size_t)(nt * 8 + kb) * 64 + lane) * 8);
            }
#pragma unroll
            for (int ti = 0; ti < 2; ti++)
#pragma unroll
                for (int tj = 0; tj < 4; tj++)
                    acc2[h][ti][tj] = __builtin_amdgcn_mfma_f32_16x16x32_bf16(
                        a[ti], b[tj], acc2[h][ti][tj], 0, 0, 0);
        }
    }

    // ---- phase-2 epilogue: cols <128 -> T2 (no bias), >=128 -> P (+b2) ----
#pragma unroll
    for (int h = 0; h < 2; h++) {
#pragma unroll
        for (int tj = 0; tj < 4; tj++) {
            int n_g = wx * 128 + (h * 4 + tj) * 16 + lm;
            float bv;
            u16* dst;
            if (n_g < 128) {
                bv = 0.f;
                dst = T2 + n_g;
            } else {
                bv = lde(b2, n_g - 128, f32);
                dst = P + (n_g - 128);
            }
#pragma unroll
            for (int ti = 0; ti < 2; ti++) {
                int rbase = row0 + rw + ti * 16 + q * 4;
#pragma unroll
                for (int r = 0; r < 4; r++) {
                    int row = rbase + r;
                    if (row < M)
                        dst[(size_t)row * 128] = f2b(acc2[h][ti][tj][r] + bv);
                }
            }
        }
    }
}

extern "C" void kernel_launch(void* const* d_in, const int* in_sizes, int n_in,
                              void* d_out, int out_size, void* d_ws, size_t ws_size,
                              hipStream_t stream) {
    const void* pf     = d_in[0];
    const int*  sid    = (const int*)d_in[1];
    const int*  ei     = (const int*)d_in[2];
    const void* ew     = d_in[3];
    const void* Wp     = d_in[4];
    const void* bp     = d_in[5];
    const void* semb   = d_in[6];
    const void* et     = d_in[7];
    const void* W1rel  = d_in[8];
    const void* b1     = d_in[9];
    const void* W1root = d_in[10];
    const void* W2rel  = d_in[11];
    const void* b2     = d_in[12];
    const void* W2root = d_in[13];

    // Workspace (~100.3 MB < proven 122.88 MB budget):
    char* w = (char*)d_ws;
    u16* agg       = (u16*)w;                    // bf16 [N,128]
    u16* T2        = (u16*)(w + 30720000);       // bf16 [N,128]
    u16* P         = (u16*)(w + 61440000);       // bf16 [N,128]
    u16* Wf1       = (u16*)(w + 92160000);       // 131072 B
    u16* Wf2       = (u16*)(w + 92291072);       // 131072 B
    int* ssrc      = (int*)(w + 92422144);       // int [E]
    u16* sw        = (u16*)(w + 96422144);       // bf16 [E]
    int* row_start = (int*)(w + 98422144);       // int [N+1]
    int* row_tmp   = (int*)(w + 98902148);
    int* cursor    = (int*)(w + 99382148);
    int* count     = (int*)(w + 99862148);
    int* bsum      = (int*)(w + 100342148);
    int* flag      = (int*)(w + 100346244);      // dtype flag
    u16* Xb        = (u16*)d_out;                // bf16 [N,128] scratch until fused_gemm done

    const int EB = (NEDGE + 255) / 256;   // 3907
    const int NB = (NNODE + 255) / 256;   // 469
    const int GB = (NNODE + 63) / 64;     // 1875

    // one-shot dtype detection
    detect_k<<<1, 64, 0, stream>>>(ew, flag);

    // CSR build (reused by both gathers)
    hipMemsetAsync(count, 0, NNODE * sizeof(int), stream);
    hist_dst<<<EB, 256, 0, stream>>>(ei, count);
    scan1<<<NB, 256, 0, stream>>>(count, row_tmp, bsum);
    scan2<<<1, 512, 0, stream>>>(bsum, NB);
    scan3<<<NB, 256, 0, stream>>>(row_tmp, bsum, row_start, cursor);
    fill_csr<<<EB, 256, 0, stream>>>(ei, ew, flag, cursor, ssrc, sw);

    // weight fragments
    prep_wf1<<<256, 256, 0, stream>>>(W1rel, W1root, flag, Wf1);
    prep_wf2<<<256, 256, 0, stream>>>(W2rel, W2root, flag, Wf2);

    // node features -> Xb (d_out)
    build_pol<<<N_POL / 2, 256, 0, stream>>>(pf, sid, Wp, bp, semb, flag, Xb);
    build_tick<<<(N_TICK * 128) / 256, 256, 0, stream>>>(et, flag, Xb);

    // layer-1 aggregation
    gather128<<<NNODE / 4, 256, 0, stream>>>(row_start, ssrc, sw, Xb, agg);

    // fused: H = relu([agg|Xb]@Wf1+b1) in LDS; [T2|P] = H@Wf2 (+b2 on P)
    fused_gemm<<<GB, 256, 0, stream>>>(agg, Xb, Wf1, Wf2, b1, b2, T2, P, flag, NNODE);

    // out = P + segment_sum(w * T2)   (d_out scratch Xb is dead now)
    gather_add<<<NNODE / 4, 256, 0, stream>>>(row_start, ssrc, sw, T2, P, flag, d_out);
}

// Round 4
// 503.895 us; speedup vs baseline: 1.1911x; 1.1458x over previous
//
#include <hip/hip_runtime.h>
#include <hip/hip_bf16.h>

typedef unsigned short u16;
using short8  = __attribute__((ext_vector_type(8))) short;
using float4v = __attribute__((ext_vector_type(4))) float;

#define N_POL  100000
#define N_TICK 20000
#define NNODE  120000
#define NEDGE  1000000
// EMB=128, HID=256, OUT=128

static __device__ __forceinline__ float b2f(u16 u) {
    return __uint_as_float(((unsigned)u) << 16);
}
static __device__ __forceinline__ u16 f2b(float f) {
    unsigned u = __float_as_uint(f);
    unsigned r = (u + 0x7FFFu + ((u >> 16) & 1u)) >> 16;
    return (u16)r;
}
static __device__ __forceinline__ float lde(const void* p, size_t i, int f32) {
    return f32 ? ((const float*)p)[i] : b2f(((const u16*)p)[i]);
}

// MFMA B-fragment address for K=256, N=256 packed weights (verified R7):
// element (k,n) -> ((n/16)*8 + k/32)*512 + (((k>>3)&3)*16 + (n&15))*8 + (k&7)
static __device__ __forceinline__ size_t frag_addr(int k, int n) {
    return ((size_t)((n >> 4) * 8 + (k >> 5)) * 64 + (((k >> 3) & 3) * 16 + (n & 15))) * 8
           + (k & 7);
}

// 16B global->LDS DMA (wave-uniform LDS base; HW adds lane*16)
static __device__ __forceinline__ void gload_lds16(const u16* g, u16* l) {
    __builtin_amdgcn_global_load_lds(
        (const __attribute__((address_space(1))) void*)g,
        (__attribute__((address_space(3))) void*)l, 16, 0, 0);
}

// ---------------- one-shot input-dtype detection ----------------
// Runtime input-dtype detection on edge_weight (uniform [0,1)). See R4/R5 notes.
// Hoisted to a single tiny kernel: consumers do one uniform load instead of a
// 64-deep serial load chain + barrier per block.
__global__ void detect_k(const void* __restrict__ ew, int* __restrict__ flag) {
    if (threadIdx.x == 0) {
        const u16* p = (const u16*)ew;
        int huge = 0, allz = 1;
        for (int i = 0; i < 128; i += 2) {
            u16 b = p[i];
            if (b != 0) allz = 0;
            float v = b2f(b);
            if (!(fabsf(v) <= 4.0f)) huge = 1;
        }
        *flag = huge | allz;
    }
}

// ---------------- node feature build ----------------
__global__ __launch_bounds__(256) void build_pol(const void* __restrict__ pf,
                                                 const int* __restrict__ sid,
                                                 const void* __restrict__ Wp,
                                                 const void* __restrict__ bp,
                                                 const void* __restrict__ semb,
                                                 const int* __restrict__ flag,
                                                 u16* __restrict__ Xb) {
    const int f32 = *flag;
    int row = blockIdx.x * 2 + (threadIdx.x >> 7);
    int j = threadIdx.x & 127;
    float s = lde(bp, j, f32);
#pragma unroll
    for (int k = 0; k < 7; k++)
        s = fmaf(lde(pf, (size_t)row * 7 + k, f32), lde(Wp, k * 128 + j, f32), s);
    s = fmaxf(s, 0.f);
    s += lde(semb, (size_t)sid[row] * 128 + j, f32);
    Xb[(size_t)row * 128 + j] = f2b(s);
}

__global__ __launch_bounds__(256) void build_tick(const void* __restrict__ et,
                                                  const int* __restrict__ flag,
                                                  u16* __restrict__ Xb) {
    const int f32 = *flag;
    int idx = blockIdx.x * 256 + threadIdx.x;
    Xb[(size_t)N_POL * 128 + idx] = f2b(lde(et, idx, f32));
}

// ---------------- weight fragment prep ----------------
// GEMM1 B[k][n]: k<128 -> W1rel[k][n], else W1root[k-128][n]; N=256.
__global__ __launch_bounds__(256) void prep_wf1(const void* __restrict__ W1rel,
                                                const void* __restrict__ W1root,
                                                const int* __restrict__ flag,
                                                u16* __restrict__ Wf) {
    const int f32 = *flag;
    int idx = blockIdx.x * 256 + threadIdx.x;   // 65536
    int k = idx >> 8, n = idx & 255;
    float v = (k < 128) ? lde(W1rel, (size_t)k * 256 + n, f32)
                        : lde(W1root, (size_t)(k - 128) * 256 + n, f32);
    Wf[frag_addr(k, n)] = f2b(v);
}

// GEMM2 B[k][n]: n<128 -> W2rel[k][n], else W2root[k][n-128]; N=256.
__global__ __launch_bounds__(256) void prep_wf2(const void* __restrict__ W2rel,
                                                const void* __restrict__ W2root,
                                                const int* __restrict__ flag,
                                                u16* __restrict__ Wf) {
    const int f32 = *flag;
    int idx = blockIdx.x * 256 + threadIdx.x;   // 65536
    int k = idx >> 8, n = idx & 255;
    float v = (n < 128) ? lde(W2rel, (size_t)k * 128 + n, f32)
                        : lde(W2root, (size_t)k * 128 + (n - 128), f32);
    Wf[frag_addr(k, n)] = f2b(v);
}

// ---------------- CSR build ----------------
__global__ __launch_bounds__(256) void hist_dst(const int* __restrict__ ei,
                                                int* __restrict__ count) {
    int e = blockIdx.x * 256 + threadIdx.x;
    if (e < NEDGE) atomicAdd(&count[ei[NEDGE + e]], 1);
}

__global__ __launch_bounds__(256) void scan1(const int* __restrict__ count,
                                             int* __restrict__ row_tmp,
                                             int* __restrict__ bsum) {
    __shared__ int sd[256];
    int t = threadIdx.x;
    int i = blockIdx.x * 256 + t;
    int c = (i < NNODE) ? count[i] : 0;
    sd[t] = c;
    __syncthreads();
#pragma unroll
    for (int off = 1; off < 256; off <<= 1) {
        int v = (t >= off) ? sd[t - off] : 0;
        __syncthreads();
        sd[t] += v;
        __syncthreads();
    }
    if (i < NNODE) row_tmp[i] = sd[t] - c;
    if (t == 255) bsum[blockIdx.x] = sd[t];
}

__global__ __launch_bounds__(512) void scan2(int* __restrict__ bsum, int nb) {
    __shared__ int sd[512];
    int t = threadIdx.x;
    int v = (t < nb) ? bsum[t] : 0;
    sd[t] = v;
    __syncthreads();
#pragma unroll
    for (int off = 1; off < 512; off <<= 1) {
        int u = (t >= off) ? sd[t - off] : 0;
        __syncthreads();
        sd[t] += u;
        __syncthreads();
    }
    if (t < nb) bsum[t] = sd[t] - v;
}

__global__ __launch_bounds__(256) void scan3(const int* __restrict__ row_tmp,
                                             const int* __restrict__ bsum,
                                             int* __restrict__ row_start,
                                             int* __restrict__ cursor) {
    int i = blockIdx.x * 256 + threadIdx.x;
    if (i < NNODE) {
        int v = row_tmp[i] + bsum[blockIdx.x];
        row_start[i] = v;
        cursor[i] = v;
    }
    if (i == 0) row_start[NNODE] = NEDGE;
}

__global__ __launch_bounds__(256) void fill_csr(const int* __restrict__ ei,
                                                const void* __restrict__ ew,
                                                const int* __restrict__ flag,
                                                int* __restrict__ cursor,
                                                int* __restrict__ ssrc,
                                                u16* __restrict__ sw) {
    const int f32 = *flag;
    int e = blockIdx.x * 256 + threadIdx.x;
    if (e >= NEDGE) return;
    int src = ei[e];
    int dst = ei[NEDGE + e];
    int pos = atomicAdd(&cursor[dst], 1);
    ssrc[pos] = src;
    sw[pos] = f2b(lde(ew, e, f32));
}

// ---------------- gather1: agg[n] = sum_e w_e * S[src_e]  (bf16 out, pitch 128) ----
__global__ __launch_bounds__(256) void gather128(const int* __restrict__ row_start,
                                                 const int* __restrict__ ssrc,
                                                 const u16* __restrict__ sw,
                                                 const u16* __restrict__ S,
                                                 u16* __restrict__ agg) {
    int n = blockIdx.x * 4 + (threadIdx.x >> 6);
    int lane = threadIdx.x & 63;
    int s0 = row_start[n], s1 = row_start[n + 1];
    float a0 = 0.f, a1 = 0.f;
    int e = s0;
    for (; e + 8 <= s1; e += 8) {
        float w[8]; ushort2 xv[8];
#pragma unroll
        for (int u = 0; u < 8; u++) {
            int sr = ssrc[e + u];
            w[u] = b2f(sw[e + u]);
            xv[u] = *(const ushort2*)(S + (size_t)sr * 128 + lane * 2);
        }
#pragma unroll
        for (int u = 0; u < 8; u++) {
            a0 = fmaf(b2f(xv[u].x), w[u], a0);
            a1 = fmaf(b2f(xv[u].y), w[u], a1);
        }
    }
    for (; e < s1; e++) {
        int sr = ssrc[e];
        float w = b2f(sw[e]);
        ushort2 xv = *(const ushort2*)(S + (size_t)sr * 128 + lane * 2);
        a0 = fmaf(b2f(xv.x), w, a0);
        a1 = fmaf(b2f(xv.y), w, a1);
    }
    ushort2 o;
    o.x = f2b(a0);
    o.y = f2b(a1);
    *(ushort2*)(agg + (size_t)n * 128 + lane * 2) = o;
}

// ---------------- gather2 + add P: out[n] = P[n] + sum_e w_e * T2[src_e] ----------
__global__ __launch_bounds__(256) void gather_add(const int* __restrict__ row_start,
                                                  const int* __restrict__ ssrc,
                                                  const u16* __restrict__ sw,
                                                  const u16* __restrict__ T2,
                                                  const u16* __restrict__ P,
                                                  const int* __restrict__ flag,
                                                  void* __restrict__ out) {
    const int f32 = *flag;
    int n = blockIdx.x * 4 + (threadIdx.x >> 6);
    int lane = threadIdx.x & 63;
    int s0 = row_start[n], s1 = row_start[n + 1];
    float a0 = 0.f, a1 = 0.f;
    int e = s0;
    for (; e + 8 <= s1; e += 8) {
        float w[8]; ushort2 xv[8];
#pragma unroll
        for (int u = 0; u < 8; u++) {
            int sr = ssrc[e + u];
            w[u] = b2f(sw[e + u]);
            xv[u] = *(const ushort2*)(T2 + (size_t)sr * 128 + lane * 2);
        }
#pragma unroll
        for (int u = 0; u < 8; u++) {
            a0 = fmaf(b2f(xv[u].x), w[u], a0);
            a1 = fmaf(b2f(xv[u].y), w[u], a1);
        }
    }
    for (; e < s1; e++) {
        int sr = ssrc[e];
        float w = b2f(sw[e]);
        ushort2 xv = *(const ushort2*)(T2 + (size_t)sr * 128 + lane * 2);
        a0 = fmaf(b2f(xv.x), w, a0);
        a1 = fmaf(b2f(xv.y), w, a1);
    }
    ushort2 pv = *(const ushort2*)(P + (size_t)n * 128 + lane * 2);
    float v0 = a0 + b2f(pv.x);
    float v1 = a1 + b2f(pv.y);
    if (f32) {
        float2 s; s.x = v0; s.y = v1;
        *(float2*)((float*)out + (size_t)n * 128 + lane * 2) = s;
    } else {
        ushort2 s; s.x = f2b(v0); s.y = f2b(v1);
        *(ushort2*)((u16*)out + (size_t)n * 128 + lane * 2) = s;
    }
}

// ---------------- fused dual MFMA GEMM (v4: v3 minus the spill-forcing bound) ------
// Phase 1: H = relu([agg|Xb] @ Wf1 + b1)   (64 rows x 256 cols)
// Phase 2: [T2 | P] = H @ Wf2 (+b2 on P half)  -> global
// Block 256 thr (4 waves 2x2: wy=row-half, wx=col-half). Wave tile 32r x 128c.
// LDSU (32 KB): A tile row-major [64 rows][32 chunks of 16B], XOR-swizzled
// (chunk_in_lds = chunk_global ^ (row&7)); then reused for H frags (A dead first).
// DMA: instr t (wave-uniform) -> LDS bytes t*1024; lanes 0-31 = row 2t (512B
// contiguous per row), 32-63 = row 2t+1. Global src pre-swizzled so each DMA
// instr fetches 16 fully-used 64B lines (2 rows x [agg|Xb]), zero redundancy.
// H frag order (phase 2 A): element (row,k) at u16 index ((k>>3)*64 + row)*8 + (k&7).
// NOTE: no min-waves launch_bounds — (256,4) forced a 64-VGPR allocation that
// spilled both accumulator arrays (418 MB scratch WRITE_SIZE, r3).
__global__ __launch_bounds__(256) void fused_gemm(const u16* __restrict__ agg,
                                                  const u16* __restrict__ Xb,
                                                  const u16* __restrict__ Wf1,
                                                  const u16* __restrict__ Wf2,
                                                  const void* __restrict__ b1,
                                                  const void* __restrict__ b2,
                                                  u16* __restrict__ T2,
                                                  u16* __restrict__ P,
                                                  const int* __restrict__ flag,
                                                  int M) {
    const int f32 = *flag;
    __shared__ u16 LDSU[32 * 64 * 8];   // 32 KB, A tile then H frags
    const int row0 = blockIdx.x * 64;
    const int wid = threadIdx.x >> 6;
    const int lane = threadIdx.x & 63;
    const int wy = wid >> 1, wx = wid & 1;
    const int q = lane >> 4, lm = lane & 15;
    const int rw = wy * 32;             // wave row base (block-local)

    // ---- stage A tile (64 rows x K=256: chunks 0-15 agg, 16-31 Xb) ----
    {
        int kqL = lane & 31;
#pragma unroll
        for (int i = 0; i < 8; i++) {
            int t = i * 4 + wid;                   // wave-uniform instr index 0..31
            int row = 2 * t + (lane >> 5);         // 0..63
            int kqG = kqL ^ (row & 7);             // pre-swizzled source chunk
            const u16* src = (kqG < 16)
                ? agg + ((size_t)(row0 + row)) * 128 + kqG * 8
                : Xb + ((size_t)(row0 + row)) * 128 + (kqG - 16) * 8;
            gload_lds16(src, LDSU + (size_t)t * 512);
        }
    }
    __syncthreads();   // drains vmcnt (global_load_lds) before any ds_read

    // ---- phase 1: MFMAs only (epilogue deferred so LDSU can be reused) ----
    float4v acc[2][2][4];   // [h][ti][tj]
#pragma unroll
    for (int h = 0; h < 2; h++)
#pragma unroll
        for (int i = 0; i < 2; i++)
#pragma unroll
            for (int j = 0; j < 4; j++) acc[h][i][j] = (float4v){0.f, 0.f, 0.f, 0.f};
#pragma unroll
    for (int kb = 0; kb < 8; kb++) {
        short8 a[2];
#pragma unroll
        for (int ti = 0; ti < 2; ti++) {
            int rl = rw + ti * 16 + lm;
            int chunk = (kb * 4 + q) ^ (rl & 7);   // XOR-swizzle read side
            a[ti] = *(const short8*)(LDSU + (size_t)rl * 256 + chunk * 8);
        }
#pragma unroll
        for (int h = 0; h < 2; h++) {
            short8 b[4];
#pragma unroll
            for (int tj = 0; tj < 4; tj++) {
                int nt = wx * 8 + h * 4 + tj;
                b[tj] = *(const short8*)(Wf1 + ((size_t)(nt * 8 + kb) * 64 + lane) * 8);
            }
#pragma unroll
            for (int ti = 0; ti < 2; ti++)
#pragma unroll
                for (int tj = 0; tj < 4; tj++)
                    acc[h][ti][tj] = __builtin_amdgcn_mfma_f32_16x16x32_bf16(
                        a[ti], b[tj], acc[h][ti][tj], 0, 0, 0);
        }
    }
    __syncthreads();   // all A reads done; LDSU now reusable for H

    // ---- phase-1 epilogue: bias + relu -> LDSU (phase-2 A-frag order) ----
#pragma unroll
    for (int h = 0; h < 2; h++) {
#pragma unroll
        for (int tj = 0; tj < 4; tj++) {
            int col = wx * 128 + (h * 4 + tj) * 16 + lm;
            float bv = lde(b1, col, f32);
            int kq2 = col >> 3, jj = col & 7;
#pragma unroll
            for (int ti = 0; ti < 2; ti++) {
                int rl = rw + ti * 16 + q * 4;
#pragma unroll
                for (int r = 0; r < 4; r++) {
                    float v = fmaxf(acc[h][ti][tj][r] + bv, 0.f);
                    LDSU[((size_t)kq2 * 64 + rl + r) * 8 + jj] = f2b(v);
                }
            }
        }
    }
    __syncthreads();

    // ---- phase 2 ----
    float4v acc2[2][2][4];
#pragma unroll
    for (int h = 0; h < 2; h++)
#pragma unroll
        for (int i = 0; i < 2; i++)
#pragma unroll
            for (int j = 0; j < 4; j++) acc2[h][i][j] = (float4v){0.f, 0.f, 0.f, 0.f};
#pragma unroll
    for (int kb = 0; kb < 8; kb++) {
        short8 a[2];
#pragma unroll
        for (int ti = 0; ti < 2; ti++) {
            int rl = rw + ti * 16 + lm;
            a[ti] = *(const short8*)(LDSU + ((size_t)(kb * 4 + q) * 64 + rl) * 8);
        }
#pragma unroll
        for (int h = 0; h < 2; h++) {
            short8 b[4];
#pragma unroll
            for (int tj = 0; tj < 4; tj++) {
                int nt = wx * 8 + h * 4 + tj;
                b[tj] = *(const short8*)(Wf2 + ((size_t)(nt * 8 + kb) * 64 + lane) * 8);
            }
#pragma unroll
            for (int ti = 0; ti < 2; ti++)
#pragma unroll
                for (int tj = 0; tj < 4; tj++)
                    acc2[h][ti][tj] = __builtin_amdgcn_mfma_f32_16x16x32_bf16(
                        a[ti], b[tj], acc2[h][ti][tj], 0, 0, 0);
        }
    }

    // ---- phase-2 epilogue: cols <128 -> T2 (no bias), >=128 -> P (+b2) ----
#pragma unroll
    for (int h = 0; h < 2; h++) {
#pragma unroll
        for (int tj = 0; tj < 4; tj++) {
            int n_g = wx * 128 + (h * 4 + tj) * 16 + lm;
            float bv;
            u16* dst;
            if (n_g < 128) {
                bv = 0.f;
                dst = T2 + n_g;
            } else {
                bv = lde(b2, n_g - 128, f32);
                dst = P + (n_g - 128);
            }
#pragma unroll
            for (int ti = 0; ti < 2; ti++) {
                int rbase = row0 + rw + ti * 16 + q * 4;
#pragma unroll
                for (int r = 0; r < 4; r++) {
                    int row = rbase + r;
                    if (row < M)
                        dst[(size_t)row * 128] = f2b(acc2[h][ti][tj][r] + bv);
                }
            }
        }
    }
}

extern "C" void kernel_launch(void* const* d_in, const int* in_sizes, int n_in,
                              void* d_out, int out_size, void* d_ws, size_t ws_size,
                              hipStream_t stream) {
    const void* pf     = d_in[0];
    const int*  sid    = (const int*)d_in[1];
    const int*  ei     = (const int*)d_in[2];
    const void* ew     = d_in[3];
    const void* Wp     = d_in[4];
    const void* bp     = d_in[5];
    const void* semb   = d_in[6];
    const void* et     = d_in[7];
    const void* W1rel  = d_in[8];
    const void* b1     = d_in[9];
    const void* W1root = d_in[10];
    const void* W2rel  = d_in[11];
    const void* b2     = d_in[12];
    const void* W2root = d_in[13];

    // Workspace (~100.3 MB < proven 122.88 MB budget):
    char* w = (char*)d_ws;
    u16* agg       = (u16*)w;                    // bf16 [N,128]
    u16* T2        = (u16*)(w + 30720000);       // bf16 [N,128]
    u16* P         = (u16*)(w + 61440000);       // bf16 [N,128]
    u16* Wf1       = (u16*)(w + 92160000);       // 131072 B
    u16* Wf2       = (u16*)(w + 92291072);       // 131072 B
    int* ssrc      = (int*)(w + 92422144);       // int [E]
    u16* sw        = (u16*)(w + 96422144);       // bf16 [E]
    int* row_start = (int*)(w + 98422144);       // int [N+1]
    int* row_tmp   = (int*)(w + 98902148);
    int* cursor    = (int*)(w + 99382148);
    int* count     = (int*)(w + 99862148);
    int* bsum      = (int*)(w + 100342148);
    int* flag      = (int*)(w + 100346244);      // dtype flag
    u16* Xb        = (u16*)d_out;                // bf16 [N,128] scratch until fused_gemm done

    const int EB = (NEDGE + 255) / 256;   // 3907
    const int NB = (NNODE + 255) / 256;   // 469
    const int GB = (NNODE + 63) / 64;     // 1875

    // one-shot dtype detection
    detect_k<<<1, 64, 0, stream>>>(ew, flag);

    // CSR build (reused by both gathers)
    hipMemsetAsync(count, 0, NNODE * sizeof(int), stream);
    hist_dst<<<EB, 256, 0, stream>>>(ei, count);
    scan1<<<NB, 256, 0, stream>>>(count, row_tmp, bsum);
    scan2<<<1, 512, 0, stream>>>(bsum, NB);
    scan3<<<NB, 256, 0, stream>>>(row_tmp, bsum, row_start, cursor);
    fill_csr<<<EB, 256, 0, stream>>>(ei, ew, flag, cursor, ssrc, sw);

    // weight fragments
    prep_wf1<<<256, 256, 0, stream>>>(W1rel, W1root, flag, Wf1);
    prep_wf2<<<256, 256, 0, stream>>>(W2rel, W2root, flag, Wf2);

    // node features -> Xb (d_out)
    build_pol<<<N_POL / 2, 256, 0, stream>>>(pf, sid, Wp, bp, semb, flag, Xb);
    build_tick<<<(N_TICK * 128) / 256, 256, 0, stream>>>(et, flag, Xb);

    // layer-1 aggregation
    gather128<<<NNODE / 4, 256, 0, stream>>>(row_start, ssrc, sw, Xb, agg);

    // fused: H = relu([agg|Xb]@Wf1+b1) in LDS; [T2|P] = H@Wf2 (+b2 on P)
    fused_gemm<<<GB, 256, 0, stream>>>(agg, Xb, Wf1, Wf2, b1, b2, T2, P, flag, NNODE);

    // out = P + segment_sum(w * T2)   (d_out scratch Xb is dead now)
    gather_add<<<NNODE / 4, 256, 0, stream>>>(row_start, ssrc, sw, T2, P, flag, d_out);
}